// Round 2
// baseline (1537.556 us; speedup 1.0000x reference)
//
#include <hip/hip_runtime.h>
#include <hip/hip_bf16.h>
#include <math.h>

#define N0c 120000
#define N1c 20000
#define N2c 6000
#define N3c 1600
#define Bc  64
#define E1c 480000
#define E2c 144000
#define E3c 38400

__device__ __forceinline__ float eluf(float x) {
    return x > 0.0f ? x : expm1f(x);
}

// monotone float -> uint mapping for atomicMax-based segment max
__device__ __forceinline__ unsigned f2sort(float f) {
    unsigned u = __float_as_uint(f);
    return (u & 0x80000000u) ? ~u : (u | 0x80000000u);
}
__device__ __forceinline__ float sort2f(unsigned u) {
    unsigned bits = (u & 0x80000000u) ? (u & 0x7FFFFFFFu) : ~u;
    return __uint_as_float(bits);
}

__global__ void segmax_scatter(const float* __restrict__ x, const int* __restrict__ cl,
                               unsigned* __restrict__ buf, int total, int shiftC) {
    int idx = blockIdx.x * blockDim.x + threadIdx.x;
    if (idx >= total) return;
    int n = idx >> shiftC;
    int c = idx - (n << shiftC);
    atomicMax(&buf[(cl[n] << shiftC) + c], f2sort(x[idx]));
}

__global__ void segmax_decode(unsigned* __restrict__ buf, int total) {
    int idx = blockIdx.x * blockDim.x + threadIdx.x;
    if (idx >= total) return;
    float f = sort2f(buf[idx]);
    unsigned b = __float_as_uint(f);
    if ((b & 0x7F800000u) == 0x7F800000u) f = 0.0f;   // !isfinite -> 0
    ((float*)buf)[idx] = f;
}

__device__ __forceinline__ void compute_basis(const float* __restrict__ pseudo, int e,
                                              float basis[8], int kidx[8]) {
    float f[3];
    int loi[3];
    #pragma unroll
    for (int d = 0; d < 3; d++) {
        float p = pseudo[e * 3 + d] * 4.0f;
        float l = floorf(p);
        l = fminf(fmaxf(l, 0.0f), 3.0f);
        f[d] = p - l;
        loi[d] = (int)l;
    }
    #pragma unroll
    for (int s = 0; s < 8; s++) {
        int b0 = s & 1, b1 = (s >> 1) & 1, b2 = (s >> 2) & 1;
        float w0 = b0 ? f[0] : 1.0f - f[0];
        float w1 = b1 ? f[1] : 1.0f - f[1];
        float w2 = b2 ? f[2] : 1.0f - f[2];
        basis[s] = w0 * w1 * w2;
        kidx[s] = (loi[0] + b0) + 5 * (loi[1] + b1) + 25 * (loi[2] + b2);
    }
}

// conv1: C_in = 1, C_out = 64. One wave per edge, lane = out channel.
__global__ void conv1_edge(const int* __restrict__ edge, const float* __restrict__ pseudo,
                           const float* __restrict__ W, const float* __restrict__ x,
                           float* __restrict__ agg, float* __restrict__ deg) {
    int t = blockIdx.x * blockDim.x + threadIdx.x;
    int e = t >> 6;
    int lane = t & 63;
    if (e >= E1c) return;
    int src = edge[e], dst = edge[E1c + e];
    float basis[8]; int kidx[8];
    compute_basis(pseudo, e, basis, kidx);
    float acc = 0.0f;
    #pragma unroll
    for (int s = 0; s < 8; s++)
        acc = fmaf(basis[s], W[(kidx[s] << 6) + lane], acc);
    float val = x[src] * acc;
    atomicAdd(&agg[(dst << 6) + lane], val);
    if (lane == 0) atomicAdd(&deg[dst], 1.0f);
}

// ---- binned spline conv (conv2/conv3): counting sort by spline cube ----

__global__ void bin_hist(const int* __restrict__ edge, int E,
                         const float* __restrict__ pseudo,
                         int* __restrict__ cube, int* __restrict__ binCnt,
                         float* __restrict__ deg) {
    int e = blockIdx.x * blockDim.x + threadIdx.x;
    if (e >= E) return;
    int c = 0, mul = 1;
    #pragma unroll
    for (int d = 0; d < 3; d++) {
        float p = pseudo[e * 3 + d] * 4.0f;
        float l = fminf(fmaxf(floorf(p), 0.0f), 3.0f);
        c += (int)l * mul;
        mul <<= 2;
    }
    cube[e] = c;
    atomicAdd(&binCnt[c], 1);
    atomicAdd(&deg[edge[E + e]], 1.0f);
}

__global__ void bin_plan(const int* __restrict__ binCnt, int* __restrict__ binStart,
                         int* __restrict__ blkPrefix) {
    if (threadIdx.x == 0 && blockIdx.x == 0) {
        int s = 0, t = 0;
        for (int c = 0; c < 64; c++) {
            binStart[c] = s;
            blkPrefix[c] = t;
            s += binCnt[c];
            t += (binCnt[c] + 255) >> 8;
        }
        blkPrefix[64] = t;
    }
}

__global__ void bin_scatter(const int* __restrict__ cube, int E,
                            const int* __restrict__ binStart, int* __restrict__ cursor,
                            int* __restrict__ order) {
    int e = blockIdx.x * blockDim.x + threadIdx.x;
    if (e >= E) return;
    int c = cube[e];
    int p = atomicAdd(&cursor[c], 1);
    order[binStart[c] + p] = e;
}

// Binned spline-conv GEMM. Block = 256 threads = 4 waves, handles up to 256
// edges of ONE cube bin. Per wave: C tile = 64 edges x 64 out-channels,
// 8x8 per thread. K = 8 taps x 64 in-channels = 512, chunked by 16.
// W read once per 256 edges (vs once per edge in round 1) -> L2 traffic /64.
template<int COUT>
__global__ __launch_bounds__(256) void spline_gemm(
    const int* __restrict__ edge, int E,
    const float* __restrict__ pseudo,
    const float* __restrict__ W,
    const float* __restrict__ x,
    const int* __restrict__ order,
    const int* __restrict__ binStart,
    const int* __restrict__ binCnt,
    const int* __restrict__ blkPrefix,
    float* __restrict__ agg)
{
    __shared__ float Bs[16][64];
    __shared__ float As[4][16][64];
    __shared__ int dstS[4][64];

    int b = blockIdx.x;
    if (b >= blkPrefix[64]) return;
    int c = 0;
    while (blkPrefix[c + 1] <= b) c++;   // <=64 scalar iters

    int cnt = binCnt[c];
    int chunk = b - blkPrefix[c];
    int w = threadIdx.x >> 6, lane = threadIdx.x & 63;
    int pos = chunk * 256 + w * 64 + lane;
    bool active = pos < cnt;
    int e = active ? order[binStart[c] + pos] : 0;

    int src = 0, dst = 0;
    float basis[8];
    #pragma unroll
    for (int s = 0; s < 8; s++) basis[s] = 0.0f;
    if (active) {
        src = edge[e];
        dst = edge[E + e];
        float f[3];
        #pragma unroll
        for (int d = 0; d < 3; d++) {
            float p = pseudo[e * 3 + d] * 4.0f;
            float l = fminf(fmaxf(floorf(p), 0.0f), 3.0f);
            f[d] = p - l;
        }
        #pragma unroll
        for (int s = 0; s < 8; s++) {
            float w0 = (s & 1) ? f[0] : 1.0f - f[0];
            float w1 = (s & 2) ? f[1] : 1.0f - f[1];
            float w2 = (s & 4) ? f[2] : 1.0f - f[2];
            basis[s] = w0 * w1 * w2;
        }
    }
    dstS[w][lane] = dst;

    int lo0 = c & 3, lo1 = (c >> 2) & 3, lo2 = c >> 4;
    int colOff = (COUT == 128) ? (blockIdx.y << 6) : 0;
    int tm = lane >> 3, tn = lane & 7;

    float acc[8][8];
    #pragma unroll
    for (int ii = 0; ii < 8; ii++)
        #pragma unroll
        for (int jj = 0; jj < 8; jj++) acc[ii][jj] = 0.0f;

    const float* xrow = x + ((size_t)src << 6);

    #pragma unroll 1
    for (int s = 0; s < 8; s++) {
        int k = (lo0 + (s & 1)) + 5 * (lo1 + ((s >> 1) & 1)) + 25 * (lo2 + (s >> 2));
        const float* Wk = W + (size_t)k * 64 * COUT + colOff;
        float bs = basis[s];
        #pragma unroll 1
        for (int ic = 0; ic < 64; ic += 16) {
            __syncthreads();   // previous chunk fully consumed
            #pragma unroll
            for (int r = w; r < 16; r += 4)
                Bs[r][lane] = Wk[(size_t)(ic + r) * COUT + lane];
            #pragma unroll
            for (int r = 0; r < 16; r += 4) {
                float4 xq = *(const float4*)(xrow + ic + r);
                As[w][r + 0][lane] = bs * xq.x;
                As[w][r + 1][lane] = bs * xq.y;
                As[w][r + 2][lane] = bs * xq.z;
                As[w][r + 3][lane] = bs * xq.w;
            }
            __syncthreads();
            #pragma unroll
            for (int r = 0; r < 16; r++) {
                float4 a0 = *(const float4*)(&As[w][r][tm * 8]);
                float4 a1 = *(const float4*)(&As[w][r][tm * 8 + 4]);
                float4 b0 = *(const float4*)(&Bs[r][tn * 8]);
                float4 b1 = *(const float4*)(&Bs[r][tn * 8 + 4]);
                float av[8] = {a0.x, a0.y, a0.z, a0.w, a1.x, a1.y, a1.z, a1.w};
                float bv[8] = {b0.x, b0.y, b0.z, b0.w, b1.x, b1.y, b1.z, b1.w};
                #pragma unroll
                for (int ii = 0; ii < 8; ii++)
                    #pragma unroll
                    for (int jj = 0; jj < 8; jj++)
                        acc[ii][jj] = fmaf(av[ii], bv[jj], acc[ii][jj]);
            }
        }
    }

    int rowBase = chunk * 256 + w * 64;
    #pragma unroll
    for (int ii = 0; ii < 8; ii++) {
        int row = tm * 8 + ii;
        if (rowBase + row < cnt) {
            int d = dstS[w][row];
            float* ap = agg + (size_t)d * COUT + colOff + tn * 8;
            #pragma unroll
            for (int jj = 0; jj < 8; jj++)
                atomicAdd(ap + jj, acc[ii][jj]);
        }
    }
}

// node update for conv1 (C_in = 1): out = elu(agg/deg + x*root + b)
__global__ void node1(const float* __restrict__ agg, const float* __restrict__ deg,
                      const float* __restrict__ xm, const float* __restrict__ root,
                      const float* __restrict__ b, float* __restrict__ out, int n_nodes) {
    int idx = blockIdx.x * blockDim.x + threadIdx.x;
    if (idx >= n_nodes * 64) return;
    int v = idx >> 6, o = idx & 63;
    float d = fmaxf(deg[v], 1.0f);
    out[idx] = eluf(agg[idx] / d + xm[v] * root[o] + b[o]);
}

// node update with 64 x COUT root matmul
template <int COUT>
__global__ void node_mm(const float* __restrict__ agg, const float* __restrict__ deg,
                        const float* __restrict__ xm, const float* __restrict__ root,
                        const float* __restrict__ b, float* __restrict__ out, int n_nodes) {
    int idx = blockIdx.x * blockDim.x + threadIdx.x;
    if (idx >= n_nodes * COUT) return;
    int v = idx / COUT, o = idx % COUT;
    const float* xr = xm + v * 64;
    float s = 0.0f;
    #pragma unroll 8
    for (int i = 0; i < 64; i++)
        s = fmaf(xr[i], root[i * COUT + o], s);
    float d = fmaxf(deg[v], 1.0f);
    out[idx] = eluf(agg[idx] / d + s + b[o]);
}

__global__ void fc1_k(const float* __restrict__ xin, const float* __restrict__ w,
                      const float* __restrict__ b, float* __restrict__ h) {
    __shared__ float xsh[1024];
    int row = blockIdx.x;
    for (int i = threadIdx.x; i < 1024; i += 256) xsh[i] = xin[row * 1024 + i];
    __syncthreads();
    int o = threadIdx.x;
    float acc = b[o];
    #pragma unroll 8
    for (int i = 0; i < 1024; i++) acc = fmaf(xsh[i], w[i * 256 + o], acc);
    h[row * 256 + o] = eluf(acc);
}

__global__ void fc2_k(const float* __restrict__ h, const float* __restrict__ w,
                      const float* __restrict__ b, float* __restrict__ out) {
    __shared__ float hs[256];
    __shared__ float lg[10];
    int row = blockIdx.x;
    int t = threadIdx.x;
    for (int i = t; i < 256; i += 64) hs[i] = h[row * 256 + i];
    __syncthreads();
    if (t < 10) {
        float acc = b[t];
        for (int i = 0; i < 256; i++) acc = fmaf(hs[i], w[i * 10 + t], acc);
        lg[t] = acc;
    }
    __syncthreads();
    if (t < 10) {
        float m = -1e30f;
        #pragma unroll
        for (int j = 0; j < 10; j++) m = fmaxf(m, lg[j]);
        float sum = 0.0f;
        #pragma unroll
        for (int j = 0; j < 10; j++) sum += expf(lg[j] - m);
        out[row * 10 + t] = lg[t] - m - logf(sum);
    }
}

extern "C" void kernel_launch(void* const* d_in, const int* in_sizes, int n_in,
                              void* d_out, int out_size, void* d_ws, size_t ws_size,
                              hipStream_t stream) {
    const float* x0      = (const float*)d_in[0];
    const int*   cluster0= (const int*)d_in[1];
    const int*   edge1   = (const int*)d_in[2];
    const float* pseudo1 = (const float*)d_in[3];
    const float* W1      = (const float*)d_in[4];
    const float* root1   = (const float*)d_in[5];
    const float* b1      = (const float*)d_in[6];
    const int*   cluster1= (const int*)d_in[7];
    const int*   edge2   = (const int*)d_in[8];
    const float* pseudo2 = (const float*)d_in[9];
    const float* W2      = (const float*)d_in[10];
    const float* root2   = (const float*)d_in[11];
    const float* b2      = (const float*)d_in[12];
    const int*   cluster2= (const int*)d_in[13];
    const int*   edge3   = (const int*)d_in[14];
    const float* pseudo3 = (const float*)d_in[15];
    const float* W3      = (const float*)d_in[16];
    const float* root3   = (const float*)d_in[17];
    const float* b3      = (const float*)d_in[18];
    const int*   cluster3= (const int*)d_in[19];
    const float* fc1_w   = (const float*)d_in[20];
    const float* fc1_b   = (const float*)d_in[21];
    const float* fc2_w   = (const float*)d_in[22];
    const float* fc2_b   = (const float*)d_in[23];
    float* out = (float*)d_out;

    float* ws = (float*)d_ws;
    size_t off = 0;
    // ---- zeroed region ----
    float* xm1  = ws + off; off += 20480;
    float* agg1 = ws + off; off += (size_t)N1c * 64;
    float* deg1 = ws + off; off += 20480;
    float* xm2  = ws + off; off += (size_t)N2c * 64;
    float* agg2 = ws + off; off += (size_t)N2c * 64;
    float* deg2 = ws + off; off += 6144;
    float* xm3  = ws + off; off += (size_t)N3c * 64;
    float* agg3 = ws + off; off += (size_t)N3c * 128;
    float* deg3 = ws + off; off += 2048;
    float* xm4  = ws + off; off += 512 * 128;
    int* binCnt2    = (int*)(ws + off); off += 64;
    int* cursor2    = (int*)(ws + off); off += 64;
    int* binStart2  = (int*)(ws + off); off += 64;
    int* blkPrefix2 = (int*)(ws + off); off += 80;
    int* binCnt3    = (int*)(ws + off); off += 64;
    int* cursor3    = (int*)(ws + off); off += 64;
    int* binStart3  = (int*)(ws + off); off += 64;
    int* blkPrefix3 = (int*)(ws + off); off += 80;
    size_t zeroFloats = off;
    // ---- non-zeroed region ----
    float* x1   = ws + off; off += (size_t)N1c * 64;
    float* x2   = ws + off; off += (size_t)N2c * 64;
    float* x3   = ws + off; off += (size_t)N3c * 128;
    float* h1   = ws + off; off += 64 * 256;
    int* cube2  = (int*)(ws + off); off += E2c;
    int* order2 = (int*)(ws + off); off += E2c;
    int* cube3  = (int*)(ws + off); off += E3c;
    int* order3 = (int*)(ws + off); off += E3c;

    hipMemsetAsync(d_ws, 0, zeroFloats * sizeof(float), stream);

    // pool 0: x0 -> xm1 (N1 x 1)
    segmax_scatter<<<(N0c + 255) / 256, 256, 0, stream>>>(x0, cluster0, (unsigned*)xm1, N0c, 0);
    segmax_decode<<<(N1c + 255) / 256, 256, 0, stream>>>((unsigned*)xm1, N1c);

    // conv1 (1 -> 64) on N1 nodes, E1 edges
    conv1_edge<<<(E1c * 64) / 256, 256, 0, stream>>>(edge1, pseudo1, W1, xm1, agg1, deg1);
    node1<<<(N1c * 64) / 256, 256, 0, stream>>>(agg1, deg1, xm1, root1, b1, x1, N1c);

    // pool 1: x1 -> xm2 (N2 x 64)
    segmax_scatter<<<(N1c * 64) / 256, 256, 0, stream>>>(x1, cluster1, (unsigned*)xm2, N1c * 64, 6);
    segmax_decode<<<(N2c * 64) / 256, 256, 0, stream>>>((unsigned*)xm2, N2c * 64);

    // conv2 (64 -> 64): bin by cube, then GEMM per bin
    bin_hist<<<(E2c + 255) / 256, 256, 0, stream>>>(edge2, E2c, pseudo2, cube2, binCnt2, deg2);
    bin_plan<<<1, 64, 0, stream>>>(binCnt2, binStart2, blkPrefix2);
    bin_scatter<<<(E2c + 255) / 256, 256, 0, stream>>>(cube2, E2c, binStart2, cursor2, order2);
    {
        int maxBlk = (E2c + 255) / 256 + 64;
        spline_gemm<64><<<dim3(maxBlk, 1), 256, 0, stream>>>(
            edge2, E2c, pseudo2, W2, xm2, order2, binStart2, binCnt2, blkPrefix2, agg2);
    }
    node_mm<64><<<(N2c * 64) / 256, 256, 0, stream>>>(agg2, deg2, xm2, root2, b2, x2, N2c);

    // pool 2: x2 -> xm3 (N3 x 64)
    segmax_scatter<<<(N2c * 64) / 256, 256, 0, stream>>>(x2, cluster2, (unsigned*)xm3, N2c * 64, 6);
    segmax_decode<<<(N3c * 64) / 256, 256, 0, stream>>>((unsigned*)xm3, N3c * 64);

    // conv3 (64 -> 128): bin by cube, then GEMM per bin
    bin_hist<<<(E3c + 255) / 256, 256, 0, stream>>>(edge3, E3c, pseudo3, cube3, binCnt3, deg3);
    bin_plan<<<1, 64, 0, stream>>>(binCnt3, binStart3, blkPrefix3);
    bin_scatter<<<(E3c + 255) / 256, 256, 0, stream>>>(cube3, E3c, binStart3, cursor3, order3);
    {
        int maxBlk = (E3c + 255) / 256 + 64;
        spline_gemm<128><<<dim3(maxBlk, 2), 256, 0, stream>>>(
            edge3, E3c, pseudo3, W3, xm3, order3, binStart3, binCnt3, blkPrefix3, agg3);
    }
    node_mm<128><<<(N3c * 128) / 256, 256, 0, stream>>>(agg3, deg3, xm3, root3, b3, x3, N3c);

    // pool 3: x3 -> xm4 (512 x 128) == (64 x 1024)
    segmax_scatter<<<(N3c * 128) / 256, 256, 0, stream>>>(x3, cluster3, (unsigned*)xm4, N3c * 128, 7);
    segmax_decode<<<(512 * 128) / 256, 256, 0, stream>>>((unsigned*)xm4, 512 * 128);

    // FC head
    fc1_k<<<64, 256, 0, stream>>>(xm4, fc1_w, fc1_b, h1);
    fc2_k<<<64, 64, 0, stream>>>(h1, fc2_w, fc2_b, out);
}

// Round 3
// 1369.560 us; speedup vs baseline: 1.1227x; 1.1227x over previous
//
#include <hip/hip_runtime.h>
#include <hip/hip_bf16.h>
#include <math.h>

#define N0c 120000
#define N1c 20000
#define N2c 6000
#define N3c 1600
#define Bc  64
#define E1c 480000
#define E2c 144000
#define E3c 38400

__device__ __forceinline__ float eluf(float x) {
    return x > 0.0f ? x : expm1f(x);
}

// monotone float -> uint mapping for atomicMax-based segment max
__device__ __forceinline__ unsigned f2sort(float f) {
    unsigned u = __float_as_uint(f);
    return (u & 0x80000000u) ? ~u : (u | 0x80000000u);
}
__device__ __forceinline__ float sort2f(unsigned u) {
    unsigned bits = (u & 0x80000000u) ? (u & 0x7FFFFFFFu) : ~u;
    return __uint_as_float(bits);
}

__global__ void segmax_scatter(const float* __restrict__ x, const int* __restrict__ cl,
                               unsigned* __restrict__ buf, int total, int shiftC) {
    int idx = blockIdx.x * blockDim.x + threadIdx.x;
    if (idx >= total) return;
    int n = idx >> shiftC;
    int c = idx - (n << shiftC);
    atomicMax(&buf[(cl[n] << shiftC) + c], f2sort(x[idx]));
}

__global__ void segmax_decode(unsigned* __restrict__ buf, int total) {
    int idx = blockIdx.x * blockDim.x + threadIdx.x;
    if (idx >= total) return;
    float f = sort2f(buf[idx]);
    unsigned b = __float_as_uint(f);
    if ((b & 0x7F800000u) == 0x7F800000u) f = 0.0f;   // !isfinite -> 0
    ((float*)buf)[idx] = f;
}

// ---- CSR by destination (for conv1 gather) ----

__global__ void csr_hist(const int* __restrict__ edge, int E, int* __restrict__ cnt) {
    int e = blockIdx.x * blockDim.x + threadIdx.x;
    if (e >= E) return;
    atomicAdd(&cnt[edge[E + e]], 1);
}

// single-block exclusive scan, n up to ~20k
__global__ void scan_excl(const int* __restrict__ cnt, int* __restrict__ start, int n) {
    __shared__ int buf[256];
    __shared__ int carryS;
    int t = threadIdx.x;
    if (t == 0) carryS = 0;
    __syncthreads();
    for (int base = 0; base < n; base += 256) {
        int i = base + t;
        int v = (i < n) ? cnt[i] : 0;
        buf[t] = v;
        __syncthreads();
        for (int ofs = 1; ofs < 256; ofs <<= 1) {
            int add = (t >= ofs) ? buf[t - ofs] : 0;
            __syncthreads();
            buf[t] += add;
            __syncthreads();
        }
        if (i < n) start[i] = carryS + buf[t] - v;
        __syncthreads();
        if (t == 0) carryS += buf[255];
        __syncthreads();
    }
    if (t == 0) start[n] = carryS;
}

__global__ void csr_scatter(const int* __restrict__ edge, int E,
                            const int* __restrict__ start, int* __restrict__ cursor,
                            int* __restrict__ eidx) {
    int e = blockIdx.x * blockDim.x + threadIdx.x;
    if (e >= E) return;
    int d = edge[E + e];
    int p = atomicAdd(&cursor[d], 1);
    eidx[start[d] + p] = e;
}

// conv1 (C_in=1, C_out=64) as dst-gather: one wave per node, lane = out ch.
// No atomics; node update (mean + root + bias + elu) fused.
__global__ void conv1_gather(const int* __restrict__ edge, const float* __restrict__ pseudo,
                             const float* __restrict__ W, const float* __restrict__ x,
                             const int* __restrict__ start, const int* __restrict__ eidx,
                             const float* __restrict__ root, const float* __restrict__ bias,
                             float* __restrict__ out) {
    int v = blockIdx.x * 4 + (threadIdx.x >> 6);
    int lane = threadIdx.x & 63;
    if (v >= N1c) return;
    int s0 = start[v], s1 = start[v + 1];
    float acc = 0.0f;
    for (int p = s0; p < s1; p++) {
        int e = eidx[p];
        int src = edge[e];
        float f[3];
        int loi[3];
        #pragma unroll
        for (int d = 0; d < 3; d++) {
            float pp = pseudo[e * 3 + d] * 4.0f;
            float l = fminf(fmaxf(floorf(pp), 0.0f), 3.0f);
            f[d] = pp - l;
            loi[d] = (int)l;
        }
        float t = 0.0f;
        #pragma unroll
        for (int s = 0; s < 8; s++) {
            int b0 = s & 1, b1 = (s >> 1) & 1, b2 = (s >> 2) & 1;
            float w0 = b0 ? f[0] : 1.0f - f[0];
            float w1 = b1 ? f[1] : 1.0f - f[1];
            float w2 = b2 ? f[2] : 1.0f - f[2];
            int k = (loi[0] + b0) + 5 * (loi[1] + b1) + 25 * (loi[2] + b2);
            t = fmaf(w0 * w1 * w2, W[(k << 6) + lane], t);
        }
        acc = fmaf(x[src], t, acc);
    }
    float d = fmaxf((float)(s1 - s0), 1.0f);
    out[(v << 6) + lane] = eluf(acc / d + x[v] * root[lane] + bias[lane]);
}

// ---- binned spline conv (conv2/conv3): counting sort by spline cube ----

__global__ void bin_hist(const int* __restrict__ edge, int E,
                         const float* __restrict__ pseudo,
                         int* __restrict__ cube, int* __restrict__ binCnt,
                         float* __restrict__ deg) {
    int e = blockIdx.x * blockDim.x + threadIdx.x;
    if (e >= E) return;
    int c = 0, mul = 1;
    #pragma unroll
    for (int d = 0; d < 3; d++) {
        float p = pseudo[e * 3 + d] * 4.0f;
        float l = fminf(fmaxf(floorf(p), 0.0f), 3.0f);
        c += (int)l * mul;
        mul <<= 2;
    }
    cube[e] = c;
    atomicAdd(&binCnt[c], 1);
    atomicAdd(&deg[edge[E + e]], 1.0f);
}

__global__ void bin_plan(const int* __restrict__ binCnt, int* __restrict__ binStart,
                         int* __restrict__ blkPrefix, int* __restrict__ chunkBin,
                         int* __restrict__ chunkOff) {
    if (threadIdx.x == 0 && blockIdx.x == 0) {
        int s = 0, t = 0;
        for (int c = 0; c < 64; c++) {
            binStart[c] = s;
            blkPrefix[c] = t;
            int nch = (binCnt[c] + 255) >> 8;
            for (int j = 0; j < nch; j++) {
                chunkBin[t + j] = c;
                chunkOff[t + j] = j;
            }
            s += binCnt[c];
            t += nch;
        }
        blkPrefix[64] = t;
    }
}

__global__ void bin_scatter(const int* __restrict__ cube, int E,
                            const int* __restrict__ binStart, int* __restrict__ cursor,
                            int* __restrict__ order) {
    int e = blockIdx.x * blockDim.x + threadIdx.x;
    if (e >= E) return;
    int c = cube[e];
    int p = atomicAdd(&cursor[c], 1);
    order[binStart[c] + p] = e;
}

// Binned spline-conv GEMM. Block = 256 threads = 4 waves, handles up to 256
// edges of ONE cube bin. Per wave: C tile = 64 edges x 64 out-channels,
// 8x8 per thread. K = 8 taps x 64 in-channels = 512, chunked by 16.
// Epilogue: LDS transpose -> wave-coalesced row atomics (no write amplification).
template<int COUT>
__global__ __launch_bounds__(256) void spline_gemm(
    const int* __restrict__ edge, int E,
    const float* __restrict__ pseudo,
    const float* __restrict__ W,
    const float* __restrict__ x,
    const int* __restrict__ order,
    const int* __restrict__ binStart,
    const int* __restrict__ binCnt,
    const int* __restrict__ blkPrefix,
    const int* __restrict__ chunkBin,
    const int* __restrict__ chunkOff,
    float* __restrict__ agg)
{
    __shared__ float Bs[16][64];
    __shared__ float As[4][16][64];
    __shared__ int dstS[4][64];

    int b = blockIdx.x;
    if (b >= blkPrefix[64]) return;
    int c = chunkBin[b];
    int chunk = chunkOff[b];

    int cnt = binCnt[c];
    int w = threadIdx.x >> 6, lane = threadIdx.x & 63;
    int pos = chunk * 256 + w * 64 + lane;
    bool active = pos < cnt;
    int e = active ? order[binStart[c] + pos] : 0;

    int src = 0, dst = 0;
    float basis[8];
    #pragma unroll
    for (int s = 0; s < 8; s++) basis[s] = 0.0f;
    if (active) {
        src = edge[e];
        dst = edge[E + e];
        float f[3];
        #pragma unroll
        for (int d = 0; d < 3; d++) {
            float p = pseudo[e * 3 + d] * 4.0f;
            float l = fminf(fmaxf(floorf(p), 0.0f), 3.0f);
            f[d] = p - l;
        }
        #pragma unroll
        for (int s = 0; s < 8; s++) {
            float w0 = (s & 1) ? f[0] : 1.0f - f[0];
            float w1 = (s & 2) ? f[1] : 1.0f - f[1];
            float w2 = (s & 4) ? f[2] : 1.0f - f[2];
            basis[s] = w0 * w1 * w2;
        }
    }
    dstS[w][lane] = dst;

    int lo0 = c & 3, lo1 = (c >> 2) & 3, lo2 = c >> 4;
    int colOff = (COUT == 128) ? (blockIdx.y << 6) : 0;
    int tm = lane >> 3, tn = lane & 7;

    float acc[8][8];
    #pragma unroll
    for (int ii = 0; ii < 8; ii++)
        #pragma unroll
        for (int jj = 0; jj < 8; jj++) acc[ii][jj] = 0.0f;

    const float* xrow = x + ((size_t)src << 6);

    #pragma unroll 1
    for (int s = 0; s < 8; s++) {
        int k = (lo0 + (s & 1)) + 5 * (lo1 + ((s >> 1) & 1)) + 25 * (lo2 + (s >> 2));
        const float* Wk = W + (size_t)k * 64 * COUT + colOff;
        float bs = basis[s];
        #pragma unroll 1
        for (int ic = 0; ic < 64; ic += 16) {
            __syncthreads();   // previous chunk fully consumed
            #pragma unroll
            for (int r = w; r < 16; r += 4)
                Bs[r][lane] = Wk[(size_t)(ic + r) * COUT + lane];
            #pragma unroll
            for (int r = 0; r < 16; r += 4) {
                float4 xq = *(const float4*)(xrow + ic + r);
                As[w][r + 0][lane] = bs * xq.x;
                As[w][r + 1][lane] = bs * xq.y;
                As[w][r + 2][lane] = bs * xq.z;
                As[w][r + 3][lane] = bs * xq.w;
            }
            __syncthreads();
            #pragma unroll
            for (int r = 0; r < 16; r++) {
                float4 a0 = *(const float4*)(&As[w][r][tm * 8]);
                float4 a1 = *(const float4*)(&As[w][r][tm * 8 + 4]);
                float4 b0 = *(const float4*)(&Bs[r][tn * 8]);
                float4 b1 = *(const float4*)(&Bs[r][tn * 8 + 4]);
                float av[8] = {a0.x, a0.y, a0.z, a0.w, a1.x, a1.y, a1.z, a1.w};
                float bv[8] = {b0.x, b0.y, b0.z, b0.w, b1.x, b1.y, b1.z, b1.w};
                #pragma unroll
                for (int ii = 0; ii < 8; ii++)
                    #pragma unroll
                    for (int jj = 0; jj < 8; jj++)
                        acc[ii][jj] = fmaf(av[ii], bv[jj], acc[ii][jj]);
            }
        }
    }

    // Epilogue: per wave, 4 passes of 16 rows through LDS (reuse As[w]),
    // then wave-coalesced atomicAdd (lane = channel) per row.
    int rowBase = chunk * 256 + w * 64;
    #pragma unroll 1
    for (int pass = 0; pass < 4; pass++) {
        __syncthreads();
        if ((tm >> 1) == pass) {
            int rl = (tm & 1) * 8;
            #pragma unroll
            for (int ii = 0; ii < 8; ii++) {
                *(float4*)(&As[w][rl + ii][tn * 8]) =
                    make_float4(acc[ii][0], acc[ii][1], acc[ii][2], acc[ii][3]);
                *(float4*)(&As[w][rl + ii][tn * 8 + 4]) =
                    make_float4(acc[ii][4], acc[ii][5], acc[ii][6], acc[ii][7]);
            }
        }
        __syncthreads();
        #pragma unroll 1
        for (int r = 0; r < 16; r++) {
            int row = pass * 16 + r;
            if (rowBase + row < cnt) {
                atomicAdd(&agg[(size_t)dstS[w][row] * COUT + colOff + lane],
                          As[w][r][lane]);
            }
        }
    }
}

// node update with 64 x COUT root matmul
template <int COUT>
__global__ void node_mm(const float* __restrict__ agg, const float* __restrict__ deg,
                        const float* __restrict__ xm, const float* __restrict__ root,
                        const float* __restrict__ b, float* __restrict__ out, int n_nodes) {
    int idx = blockIdx.x * blockDim.x + threadIdx.x;
    if (idx >= n_nodes * COUT) return;
    int v = idx / COUT, o = idx % COUT;
    const float* xr = xm + v * 64;
    float s = 0.0f;
    #pragma unroll 8
    for (int i = 0; i < 64; i++)
        s = fmaf(xr[i], root[i * COUT + o], s);
    float d = fmaxf(deg[v], 1.0f);
    out[idx] = eluf(agg[idx] / d + s + b[o]);
}

__global__ void fc1_k(const float* __restrict__ xin, const float* __restrict__ w,
                      const float* __restrict__ b, float* __restrict__ h) {
    __shared__ float xsh[1024];
    int row = blockIdx.x;
    for (int i = threadIdx.x; i < 1024; i += 256) xsh[i] = xin[row * 1024 + i];
    __syncthreads();
    int o = threadIdx.x;
    float acc = b[o];
    #pragma unroll 8
    for (int i = 0; i < 1024; i++) acc = fmaf(xsh[i], w[i * 256 + o], acc);
    h[row * 256 + o] = eluf(acc);
}

__global__ void fc2_k(const float* __restrict__ h, const float* __restrict__ w,
                      const float* __restrict__ b, float* __restrict__ out) {
    __shared__ float hs[256];
    __shared__ float lg[10];
    int row = blockIdx.x;
    int t = threadIdx.x;
    for (int i = t; i < 256; i += 64) hs[i] = h[row * 256 + i];
    __syncthreads();
    if (t < 10) {
        float acc = b[t];
        for (int i = 0; i < 256; i++) acc = fmaf(hs[i], w[i * 10 + t], acc);
        lg[t] = acc;
    }
    __syncthreads();
    if (t < 10) {
        float m = -1e30f;
        #pragma unroll
        for (int j = 0; j < 10; j++) m = fmaxf(m, lg[j]);
        float sum = 0.0f;
        #pragma unroll
        for (int j = 0; j < 10; j++) sum += expf(lg[j] - m);
        out[row * 10 + t] = lg[t] - m - logf(sum);
    }
}

extern "C" void kernel_launch(void* const* d_in, const int* in_sizes, int n_in,
                              void* d_out, int out_size, void* d_ws, size_t ws_size,
                              hipStream_t stream) {
    const float* x0      = (const float*)d_in[0];
    const int*   cluster0= (const int*)d_in[1];
    const int*   edge1   = (const int*)d_in[2];
    const float* pseudo1 = (const float*)d_in[3];
    const float* W1      = (const float*)d_in[4];
    const float* root1   = (const float*)d_in[5];
    const float* b1      = (const float*)d_in[6];
    const int*   cluster1= (const int*)d_in[7];
    const int*   edge2   = (const int*)d_in[8];
    const float* pseudo2 = (const float*)d_in[9];
    const float* W2      = (const float*)d_in[10];
    const float* root2   = (const float*)d_in[11];
    const float* b2      = (const float*)d_in[12];
    const int*   cluster2= (const int*)d_in[13];
    const int*   edge3   = (const int*)d_in[14];
    const float* pseudo3 = (const float*)d_in[15];
    const float* W3      = (const float*)d_in[16];
    const float* root3   = (const float*)d_in[17];
    const float* b3      = (const float*)d_in[18];
    const int*   cluster3= (const int*)d_in[19];
    const float* fc1_w   = (const float*)d_in[20];
    const float* fc1_b   = (const float*)d_in[21];
    const float* fc2_w   = (const float*)d_in[22];
    const float* fc2_b   = (const float*)d_in[23];
    float* out = (float*)d_out;

    float* ws = (float*)d_ws;
    size_t off = 0;
    // ---- zeroed region ----
    float* xm1  = ws + off; off += 20480;
    float* xm2  = ws + off; off += (size_t)N2c * 64;
    float* agg2 = ws + off; off += (size_t)N2c * 64;
    float* deg2 = ws + off; off += 6144;
    float* xm3  = ws + off; off += (size_t)N3c * 64;
    float* agg3 = ws + off; off += (size_t)N3c * 128;
    float* deg3 = ws + off; off += 2048;
    float* xm4  = ws + off; off += 512 * 128;
    int* binCnt2 = (int*)(ws + off); off += 64;
    int* cursor2 = (int*)(ws + off); off += 64;
    int* binCnt3 = (int*)(ws + off); off += 64;
    int* cursor3 = (int*)(ws + off); off += 64;
    int* cnt1    = (int*)(ws + off); off += N1c;
    int* cursorD1= (int*)(ws + off); off += N1c;
    size_t zeroFloats = off;
    // ---- non-zeroed region (fully written before read every launch) ----
    float* x1   = ws + off; off += (size_t)N1c * 64;
    float* x2   = ws + off; off += (size_t)N2c * 64;
    float* x3   = ws + off; off += (size_t)N3c * 128;
    float* h1   = ws + off; off += 64 * 256;
    int* cube2     = (int*)(ws + off); off += E2c;
    int* order2    = (int*)(ws + off); off += E2c;
    int* cube3     = (int*)(ws + off); off += E3c;
    int* order3    = (int*)(ws + off); off += E3c;
    int* eidx1     = (int*)(ws + off); off += E1c;
    int* start1    = (int*)(ws + off); off += N1c + 1;
    int* binStart2 = (int*)(ws + off); off += 64;
    int* blkPrefix2= (int*)(ws + off); off += 80;
    int* chunkBin2 = (int*)(ws + off); off += 704;
    int* chunkOff2 = (int*)(ws + off); off += 704;
    int* binStart3 = (int*)(ws + off); off += 64;
    int* blkPrefix3= (int*)(ws + off); off += 80;
    int* chunkBin3 = (int*)(ws + off); off += 256;
    int* chunkOff3 = (int*)(ws + off); off += 256;

    hipMemsetAsync(d_ws, 0, zeroFloats * sizeof(float), stream);

    // pool 0: x0 -> xm1 (N1 x 1)
    segmax_scatter<<<(N0c + 255) / 256, 256, 0, stream>>>(x0, cluster0, (unsigned*)xm1, N0c, 0);
    segmax_decode<<<(N1c + 255) / 256, 256, 0, stream>>>((unsigned*)xm1, N1c);

    // conv1 (1 -> 64): dst-CSR build + gather (no atomics in hot kernel)
    csr_hist<<<(E1c + 255) / 256, 256, 0, stream>>>(edge1, E1c, cnt1);
    scan_excl<<<1, 256, 0, stream>>>(cnt1, start1, N1c);
    csr_scatter<<<(E1c + 255) / 256, 256, 0, stream>>>(edge1, E1c, start1, cursorD1, eidx1);
    conv1_gather<<<(N1c + 3) / 4, 256, 0, stream>>>(edge1, pseudo1, W1, xm1,
                                                    start1, eidx1, root1, b1, x1);

    // pool 1: x1 -> xm2 (N2 x 64)
    segmax_scatter<<<(N1c * 64) / 256, 256, 0, stream>>>(x1, cluster1, (unsigned*)xm2, N1c * 64, 6);
    segmax_decode<<<(N2c * 64) / 256, 256, 0, stream>>>((unsigned*)xm2, N2c * 64);

    // conv2 (64 -> 64): bin by cube, then GEMM per bin
    bin_hist<<<(E2c + 255) / 256, 256, 0, stream>>>(edge2, E2c, pseudo2, cube2, binCnt2, deg2);
    bin_plan<<<1, 64, 0, stream>>>(binCnt2, binStart2, blkPrefix2, chunkBin2, chunkOff2);
    bin_scatter<<<(E2c + 255) / 256, 256, 0, stream>>>(cube2, E2c, binStart2, cursor2, order2);
    {
        int maxBlk = (E2c + 255) / 256 + 64;
        spline_gemm<64><<<dim3(maxBlk, 1), 256, 0, stream>>>(
            edge2, E2c, pseudo2, W2, xm2, order2, binStart2, binCnt2, blkPrefix2,
            chunkBin2, chunkOff2, agg2);
    }
    node_mm<64><<<(N2c * 64) / 256, 256, 0, stream>>>(agg2, deg2, xm2, root2, b2, x2, N2c);

    // pool 2: x2 -> xm3 (N3 x 64)
    segmax_scatter<<<(N2c * 64) / 256, 256, 0, stream>>>(x2, cluster2, (unsigned*)xm3, N2c * 64, 6);
    segmax_decode<<<(N3c * 64) / 256, 256, 0, stream>>>((unsigned*)xm3, N3c * 64);

    // conv3 (64 -> 128): bin by cube, then GEMM per bin
    bin_hist<<<(E3c + 255) / 256, 256, 0, stream>>>(edge3, E3c, pseudo3, cube3, binCnt3, deg3);
    bin_plan<<<1, 64, 0, stream>>>(binCnt3, binStart3, blkPrefix3, chunkBin3, chunkOff3);
    bin_scatter<<<(E3c + 255) / 256, 256, 0, stream>>>(cube3, E3c, binStart3, cursor3, order3);
    {
        int maxBlk = (E3c + 255) / 256 + 64;
        spline_gemm<128><<<dim3(maxBlk, 2), 256, 0, stream>>>(
            edge3, E3c, pseudo3, W3, xm3, order3, binStart3, binCnt3, blkPrefix3,
            chunkBin3, chunkOff3, agg3);
    }
    node_mm<128><<<(N3c * 128) / 256, 256, 0, stream>>>(agg3, deg3, xm3, root3, b3, x3, N3c);

    // pool 3: x3 -> xm4 (512 x 128) == (64 x 1024)
    segmax_scatter<<<(N3c * 128) / 256, 256, 0, stream>>>(x3, cluster3, (unsigned*)xm4, N3c * 128, 7);
    segmax_decode<<<(512 * 128) / 256, 256, 0, stream>>>((unsigned*)xm4, 512 * 128);

    // FC head
    fc1_k<<<64, 256, 0, stream>>>(xm4, fc1_w, fc1_b, h1);
    fc2_k<<<64, 64, 0, stream>>>(h1, fc2_w, fc2_b, out);
}

// Round 4
// 1329.685 us; speedup vs baseline: 1.1563x; 1.0300x over previous
//
#include <hip/hip_runtime.h>
#include <hip/hip_bf16.h>
#include <math.h>

#define N0c 120000
#define N1c 20000
#define N2c 6000
#define N3c 1600
#define Bc  64
#define E1c 480000
#define E2c 144000
#define E3c 38400

__device__ __forceinline__ float eluf(float x) {
    return x > 0.0f ? x : expm1f(x);
}

// monotone float -> uint mapping for atomicMax-based segment max
__device__ __forceinline__ unsigned f2sort(float f) {
    unsigned u = __float_as_uint(f);
    return (u & 0x80000000u) ? ~u : (u | 0x80000000u);
}
__device__ __forceinline__ float sort2f(unsigned u) {
    unsigned bits = (u & 0x80000000u) ? (u & 0x7FFFFFFFu) : ~u;
    return __uint_as_float(bits);
}

__global__ void segmax_scatter(const float* __restrict__ x, const int* __restrict__ cl,
                               unsigned* __restrict__ buf, int total, int shiftC) {
    int idx = blockIdx.x * blockDim.x + threadIdx.x;
    if (idx >= total) return;
    int n = idx >> shiftC;
    int c = idx - (n << shiftC);
    atomicMax(&buf[(cl[n] << shiftC) + c], f2sort(x[idx]));
}

__global__ void segmax_decode(unsigned* __restrict__ buf, int total) {
    int idx = blockIdx.x * blockDim.x + threadIdx.x;
    if (idx >= total) return;
    float f = sort2f(buf[idx]);
    unsigned b = __float_as_uint(f);
    if ((b & 0x7F800000u) == 0x7F800000u) f = 0.0f;   // !isfinite -> 0
    ((float*)buf)[idx] = f;
}

// ---- conv1 (C_in=1): accumulate per-dst knot weights T[dst][k], then GEMM ----
// T[dst,k] = sum_{e->dst} sum_s x[src(e)] * basis_s(e) * [kidx_s(e)==k]
// agg[dst,:] = T[dst,:] @ W1   (125 x 64)

__global__ void conv1_tap(const int* __restrict__ edge, const float* __restrict__ pseudo,
                          const float* __restrict__ x, float* __restrict__ T,
                          float* __restrict__ deg) {
    int e = blockIdx.x * blockDim.x + threadIdx.x;
    if (e >= E1c) return;
    int src = edge[e], dst = edge[E1c + e];
    float xv = x[src];
    float f[3];
    int loi[3];
    #pragma unroll
    for (int d = 0; d < 3; d++) {
        float pp = pseudo[e * 3 + d] * 4.0f;
        float l = fminf(fmaxf(floorf(pp), 0.0f), 3.0f);
        f[d] = pp - l;
        loi[d] = (int)l;
    }
    float* Trow = T + ((size_t)dst << 7);
    int kbase = loi[0] + 5 * loi[1] + 25 * loi[2];
    #pragma unroll
    for (int s = 0; s < 8; s++) {
        int b0 = s & 1, b1 = (s >> 1) & 1, b2 = (s >> 2) & 1;
        float w0 = b0 ? f[0] : 1.0f - f[0];
        float w1 = b1 ? f[1] : 1.0f - f[1];
        float w2 = b2 ? f[2] : 1.0f - f[2];
        int k = kbase + b0 + 5 * b1 + 25 * b2;
        atomicAdd(&Trow[k], xv * w0 * w1 * w2);
    }
    atomicAdd(&deg[dst], 1.0f);
}

// block = 256 = 4 nodes x 64 ch; fused mean + root + bias + elu
__global__ __launch_bounds__(256) void conv1_gemm(
    const float* __restrict__ T, const float* __restrict__ deg,
    const float* __restrict__ xm, const float* __restrict__ W,
    const float* __restrict__ root, const float* __restrict__ bias,
    float* __restrict__ out) {
    __shared__ float Ts[4][128];
    int v0 = blockIdx.x * 4;
    int w = threadIdx.x >> 6, lane = threadIdx.x & 63;
    for (int j = threadIdx.x; j < 512; j += 256) {
        int nv = j >> 7, k = j & 127;
        int vv = v0 + nv;
        Ts[nv][k] = (vv < N1c && k < 125) ? T[((size_t)vv << 7) + k] : 0.0f;
    }
    __syncthreads();
    int v = v0 + w;
    if (v >= N1c) return;
    float s = 0.0f;
    #pragma unroll 5
    for (int k = 0; k < 125; k++)
        s = fmaf(Ts[w][k], W[(k << 6) + lane], s);
    float d = fmaxf(deg[v], 1.0f);
    out[((size_t)v << 6) + lane] = eluf(s / d + xm[v] * root[lane] + bias[lane]);
}

// ---- binned spline conv (conv2/conv3): counting sort by spline cube ----

__global__ void bin_hist(const int* __restrict__ edge, int E,
                         const float* __restrict__ pseudo,
                         int* __restrict__ cube, int* __restrict__ binCnt,
                         float* __restrict__ deg) {
    int e = blockIdx.x * blockDim.x + threadIdx.x;
    if (e >= E) return;
    int c = 0, mul = 1;
    #pragma unroll
    for (int d = 0; d < 3; d++) {
        float p = pseudo[e * 3 + d] * 4.0f;
        float l = fminf(fmaxf(floorf(p), 0.0f), 3.0f);
        c += (int)l * mul;
        mul <<= 2;
    }
    cube[e] = c;
    atomicAdd(&binCnt[c], 1);
    atomicAdd(&deg[edge[E + e]], 1.0f);
}

// 64 threads; LDS-based scan (no serial dependent global loads)
__global__ void bin_plan(const int* __restrict__ binCnt, int* __restrict__ binStart,
                         int* __restrict__ blkPrefix, int* __restrict__ chunkBin,
                         int* __restrict__ chunkOff) {
    __shared__ int cs[64], ss[64], ps[64];
    int t = threadIdx.x;
    cs[t] = binCnt[t];
    __syncthreads();
    if (t == 0) {
        int s = 0, p = 0;
        for (int c = 0; c < 64; c++) {
            ss[c] = s; ps[c] = p;
            s += cs[c];
            p += (cs[c] + 255) >> 8;
        }
        blkPrefix[64] = p;
    }
    __syncthreads();
    binStart[t] = ss[t];
    blkPrefix[t] = ps[t];
    int nch = (cs[t] + 255) >> 8;
    for (int j = 0; j < nch; j++) {
        chunkBin[ps[t] + j] = t;
        chunkOff[ps[t] + j] = j;
    }
}

__global__ void bin_scatter(const int* __restrict__ cube, int E,
                            const int* __restrict__ binStart, int* __restrict__ cursor,
                            int* __restrict__ order) {
    int e = blockIdx.x * blockDim.x + threadIdx.x;
    if (e >= E) return;
    int c = cube[e];
    int p = atomicAdd(&cursor[c], 1);
    order[binStart[c] + p] = e;
}

// Binned spline-conv GEMM v2:
//  - ic (K-chunk of 16 in-channels) OUTER, tap s INNER: raw x staged in LDS
//    once per ic (8x less scattered global traffic than v1).
//  - basis applied at FMA time from per-wave LDS table (8 mults / K-step).
//  - K-split by tap half via blockIdx.z (2x blocks -> ~5 waves/SIMD).
// Block = 256 thr = 4 waves; wave = 64 edges x 64 out-ch, 8x8 per thread.
template<int COUT>
__global__ __launch_bounds__(256) void spline_gemm(
    const int* __restrict__ edge, int E,
    const float* __restrict__ pseudo,
    const float* __restrict__ W,
    const float* __restrict__ x,
    const int* __restrict__ order,
    const int* __restrict__ binStart,
    const int* __restrict__ binCnt,
    const int* __restrict__ blkPrefix,
    const int* __restrict__ chunkBin,
    const int* __restrict__ chunkOff,
    float* __restrict__ agg)
{
    __shared__ float Bs[16][64];
    __shared__ float Xs[4][16][64];
    __shared__ float bsS[4][64][4];
    __shared__ int dstS[4][64];

    int b = blockIdx.x;
    if (b >= blkPrefix[64]) return;
    int c = chunkBin[b];
    int chunk = chunkOff[b];
    int cnt = binCnt[c];
    int z = blockIdx.z;   // tap half: taps s = z*4 + t

    int w = threadIdx.x >> 6, lane = threadIdx.x & 63;
    int pos = chunk * 256 + w * 64 + lane;
    bool active = pos < cnt;
    int e = active ? order[binStart[c] + pos] : 0;

    int src = 0, dst = 0;
    float f0 = 0.0f, f1 = 0.0f, f2 = 0.0f;
    if (active) {
        src = edge[e];
        dst = edge[E + e];
        float p0 = pseudo[e * 3 + 0] * 4.0f;
        float p1 = pseudo[e * 3 + 1] * 4.0f;
        float p2 = pseudo[e * 3 + 2] * 4.0f;
        f0 = p0 - fminf(fmaxf(floorf(p0), 0.0f), 3.0f);
        f1 = p1 - fminf(fmaxf(floorf(p1), 0.0f), 3.0f);
        f2 = p2 - fminf(fmaxf(floorf(p2), 0.0f), 3.0f);
    }
    dstS[w][lane] = dst;
    {
        float w2 = z ? f2 : 1.0f - f2;
        #pragma unroll
        for (int t = 0; t < 4; t++) {
            float w0 = (t & 1) ? f0 : 1.0f - f0;
            float w1 = (t & 2) ? f1 : 1.0f - f1;
            bsS[w][lane][t] = active ? (w0 * w1 * w2) : 0.0f;
        }
    }

    int lo0 = c & 3, lo1 = (c >> 2) & 3, lo2 = c >> 4;
    int kbase = lo0 + 5 * lo1 + 25 * (lo2 + z);
    int colOff = (COUT == 128) ? (blockIdx.y << 6) : 0;
    int tm = lane >> 3, tn = lane & 7;

    float acc[8][8];
    #pragma unroll
    for (int ii = 0; ii < 8; ii++)
        #pragma unroll
        for (int jj = 0; jj < 8; jj++) acc[ii][jj] = 0.0f;

    const float* xrow = x + ((size_t)src << 6);

    #pragma unroll 1
    for (int ic = 0; ic < 64; ic += 16) {
        __syncthreads();   // prev round's Bs & Xs fully consumed
        #pragma unroll
        for (int r = 0; r < 16; r += 4) {
            float4 xq = *(const float4*)(xrow + ic + r);
            Xs[w][r + 0][lane] = xq.x;
            Xs[w][r + 1][lane] = xq.y;
            Xs[w][r + 2][lane] = xq.z;
            Xs[w][r + 3][lane] = xq.w;
        }
        #pragma unroll 1
        for (int t = 0; t < 4; t++) {
            int k = kbase + (t & 1) + 5 * (t >> 1);
            const float* Wk = W + (size_t)k * 64 * COUT + colOff;
            if (t > 0) __syncthreads();   // Bs consumed by all waves
            #pragma unroll
            for (int r = w; r < 16; r += 4)
                Bs[r][lane] = Wk[(size_t)(ic + r) * COUT + lane];
            __syncthreads();
            float bsf[8];
            #pragma unroll
            for (int ii = 0; ii < 8; ii++) bsf[ii] = bsS[w][tm * 8 + ii][t];
            #pragma unroll
            for (int r = 0; r < 16; r++) {
                float4 a0 = *(const float4*)(&Xs[w][r][tm * 8]);
                float4 a1 = *(const float4*)(&Xs[w][r][tm * 8 + 4]);
                float4 b0 = *(const float4*)(&Bs[r][tn * 8]);
                float4 b1 = *(const float4*)(&Bs[r][tn * 8 + 4]);
                float av[8] = {a0.x * bsf[0], a0.y * bsf[1], a0.z * bsf[2], a0.w * bsf[3],
                               a1.x * bsf[4], a1.y * bsf[5], a1.z * bsf[6], a1.w * bsf[7]};
                float bv[8] = {b0.x, b0.y, b0.z, b0.w, b1.x, b1.y, b1.z, b1.w};
                #pragma unroll
                for (int ii = 0; ii < 8; ii++)
                    #pragma unroll
                    for (int jj = 0; jj < 8; jj++)
                        acc[ii][jj] = fmaf(av[ii], bv[jj], acc[ii][jj]);
            }
        }
    }

    // Epilogue: wave-private transpose through Xs[w], then coalesced row
    // atomics (lane = channel). No __syncthreads needed: Xs[w] is wave-local.
    int rowBase = chunk * 256 + w * 64;
    #pragma unroll 1
    for (int pass = 0; pass < 4; pass++) {
        if ((tm >> 1) == pass) {
            int rl = (tm & 1) * 8;
            #pragma unroll
            for (int ii = 0; ii < 8; ii++) {
                *(float4*)(&Xs[w][rl + ii][tn * 8]) =
                    make_float4(acc[ii][0], acc[ii][1], acc[ii][2], acc[ii][3]);
                *(float4*)(&Xs[w][rl + ii][tn * 8 + 4]) =
                    make_float4(acc[ii][4], acc[ii][5], acc[ii][6], acc[ii][7]);
            }
        }
        __builtin_amdgcn_wave_barrier();
        #pragma unroll 1
        for (int r = 0; r < 16; r++) {
            int row = pass * 16 + r;
            if (rowBase + row < cnt) {
                atomicAdd(&agg[(size_t)dstS[w][row] * COUT + colOff + lane],
                          Xs[w][r][lane]);
            }
        }
        __builtin_amdgcn_wave_barrier();
    }
}

// node update with 64 x COUT root matmul
template <int COUT>
__global__ void node_mm(const float* __restrict__ agg, const float* __restrict__ deg,
                        const float* __restrict__ xm, const float* __restrict__ root,
                        const float* __restrict__ b, float* __restrict__ out, int n_nodes) {
    int idx = blockIdx.x * blockDim.x + threadIdx.x;
    if (idx >= n_nodes * COUT) return;
    int v = idx / COUT, o = idx % COUT;
    const float* xr = xm + v * 64;
    float s = 0.0f;
    #pragma unroll 8
    for (int i = 0; i < 64; i++)
        s = fmaf(xr[i], root[i * COUT + o], s);
    float d = fmaxf(deg[v], 1.0f);
    out[idx] = eluf(agg[idx] / d + s + b[o]);
}

__global__ void fc1_k(const float* __restrict__ xin, const float* __restrict__ w,
                      const float* __restrict__ b, float* __restrict__ h) {
    __shared__ float xsh[1024];
    int row = blockIdx.x;
    for (int i = threadIdx.x; i < 1024; i += 256) xsh[i] = xin[row * 1024 + i];
    __syncthreads();
    int o = threadIdx.x;
    float acc = b[o];
    #pragma unroll 8
    for (int i = 0; i < 1024; i++) acc = fmaf(xsh[i], w[i * 256 + o], acc);
    h[row * 256 + o] = eluf(acc);
}

__global__ void fc2_k(const float* __restrict__ h, const float* __restrict__ w,
                      const float* __restrict__ b, float* __restrict__ out) {
    __shared__ float hs[256];
    __shared__ float lg[10];
    int row = blockIdx.x;
    int t = threadIdx.x;
    for (int i = t; i < 256; i += 64) hs[i] = h[row * 256 + i];
    __syncthreads();
    if (t < 10) {
        float acc = b[t];
        for (int i = 0; i < 256; i++) acc = fmaf(hs[i], w[i * 10 + t], acc);
        lg[t] = acc;
    }
    __syncthreads();
    if (t < 10) {
        float m = -1e30f;
        #pragma unroll
        for (int j = 0; j < 10; j++) m = fmaxf(m, lg[j]);
        float sum = 0.0f;
        #pragma unroll
        for (int j = 0; j < 10; j++) sum += expf(lg[j] - m);
        out[row * 10 + t] = lg[t] - m - logf(sum);
    }
}

extern "C" void kernel_launch(void* const* d_in, const int* in_sizes, int n_in,
                              void* d_out, int out_size, void* d_ws, size_t ws_size,
                              hipStream_t stream) {
    const float* x0      = (const float*)d_in[0];
    const int*   cluster0= (const int*)d_in[1];
    const int*   edge1   = (const int*)d_in[2];
    const float* pseudo1 = (const float*)d_in[3];
    const float* W1      = (const float*)d_in[4];
    const float* root1   = (const float*)d_in[5];
    const float* b1      = (const float*)d_in[6];
    const int*   cluster1= (const int*)d_in[7];
    const int*   edge2   = (const int*)d_in[8];
    const float* pseudo2 = (const float*)d_in[9];
    const float* W2      = (const float*)d_in[10];
    const float* root2   = (const float*)d_in[11];
    const float* b2      = (const float*)d_in[12];
    const int*   cluster2= (const int*)d_in[13];
    const int*   edge3   = (const int*)d_in[14];
    const float* pseudo3 = (const float*)d_in[15];
    const float* W3      = (const float*)d_in[16];
    const float* root3   = (const float*)d_in[17];
    const float* b3      = (const float*)d_in[18];
    const int*   cluster3= (const int*)d_in[19];
    const float* fc1_w   = (const float*)d_in[20];
    const float* fc1_b   = (const float*)d_in[21];
    const float* fc2_w   = (const float*)d_in[22];
    const float* fc2_b   = (const float*)d_in[23];
    float* out = (float*)d_out;

    float* ws = (float*)d_ws;
    size_t off = 0;
    // ---- zeroed region ----
    float* xm1  = ws + off; off += 20480;
    float* T1   = ws + off; off += (size_t)N1c * 128;
    float* deg1 = ws + off; off += 20480;
    float* xm2  = ws + off; off += (size_t)N2c * 64;
    float* agg2 = ws + off; off += (size_t)N2c * 64;
    float* deg2 = ws + off; off += 6144;
    float* xm3  = ws + off; off += (size_t)N3c * 64;
    float* agg3 = ws + off; off += (size_t)N3c * 128;
    float* deg3 = ws + off; off += 2048;
    float* xm4  = ws + off; off += 512 * 128;
    int* binCnt2 = (int*)(ws + off); off += 64;
    int* cursor2 = (int*)(ws + off); off += 64;
    int* binCnt3 = (int*)(ws + off); off += 64;
    int* cursor3 = (int*)(ws + off); off += 64;
    size_t zeroFloats = off;
    // ---- non-zeroed region (fully written before read every launch) ----
    float* x1   = ws + off; off += (size_t)N1c * 64;
    float* x2   = ws + off; off += (size_t)N2c * 64;
    float* x3   = ws + off; off += (size_t)N3c * 128;
    float* h1   = ws + off; off += 64 * 256;
    int* cube2     = (int*)(ws + off); off += E2c;
    int* order2    = (int*)(ws + off); off += E2c;
    int* cube3     = (int*)(ws + off); off += E3c;
    int* order3    = (int*)(ws + off); off += E3c;
    int* binStart2 = (int*)(ws + off); off += 64;
    int* blkPrefix2= (int*)(ws + off); off += 80;
    int* chunkBin2 = (int*)(ws + off); off += 704;
    int* chunkOff2 = (int*)(ws + off); off += 704;
    int* binStart3 = (int*)(ws + off); off += 64;
    int* blkPrefix3= (int*)(ws + off); off += 80;
    int* chunkBin3 = (int*)(ws + off); off += 256;
    int* chunkOff3 = (int*)(ws + off); off += 256;

    hipMemsetAsync(d_ws, 0, zeroFloats * sizeof(float), stream);

    // pool 0: x0 -> xm1 (N1 x 1)
    segmax_scatter<<<(N0c + 255) / 256, 256, 0, stream>>>(x0, cluster0, (unsigned*)xm1, N0c, 0);
    segmax_decode<<<(N1c + 255) / 256, 256, 0, stream>>>((unsigned*)xm1, N1c);

    // conv1 (1 -> 64): knot-weight accumulation + tiny GEMM (fused node update)
    conv1_tap<<<(E1c + 255) / 256, 256, 0, stream>>>(edge1, pseudo1, xm1, T1, deg1);
    conv1_gemm<<<(N1c + 3) / 4, 256, 0, stream>>>(T1, deg1, xm1, W1, root1, b1, x1);

    // pool 1: x1 -> xm2 (N2 x 64)
    segmax_scatter<<<(N1c * 64) / 256, 256, 0, stream>>>(x1, cluster1, (unsigned*)xm2, N1c * 64, 6);
    segmax_decode<<<(N2c * 64) / 256, 256, 0, stream>>>((unsigned*)xm2, N2c * 64);

    // conv2 (64 -> 64): bin by cube, then GEMM per bin (K-split by tap half)
    bin_hist<<<(E2c + 255) / 256, 256, 0, stream>>>(edge2, E2c, pseudo2, cube2, binCnt2, deg2);
    bin_plan<<<1, 64, 0, stream>>>(binCnt2, binStart2, blkPrefix2, chunkBin2, chunkOff2);
    bin_scatter<<<(E2c + 255) / 256, 256, 0, stream>>>(cube2, E2c, binStart2, cursor2, order2);
    {
        int maxBlk = (E2c + 255) / 256 + 64;
        spline_gemm<64><<<dim3(maxBlk, 1, 2), 256, 0, stream>>>(
            edge2, E2c, pseudo2, W2, xm2, order2, binStart2, binCnt2, blkPrefix2,
            chunkBin2, chunkOff2, agg2);
    }
    node_mm<64><<<(N2c * 64) / 256, 256, 0, stream>>>(agg2, deg2, xm2, root2, b2, x2, N2c);

    // pool 2: x2 -> xm3 (N3 x 64)
    segmax_scatter<<<(N2c * 64) / 256, 256, 0, stream>>>(x2, cluster2, (unsigned*)xm3, N2c * 64, 6);
    segmax_decode<<<(N3c * 64) / 256, 256, 0, stream>>>((unsigned*)xm3, N3c * 64);

    // conv3 (64 -> 128): bin by cube, then GEMM per bin
    bin_hist<<<(E3c + 255) / 256, 256, 0, stream>>>(edge3, E3c, pseudo3, cube3, binCnt3, deg3);
    bin_plan<<<1, 64, 0, stream>>>(binCnt3, binStart3, blkPrefix3, chunkBin3, chunkOff3);
    bin_scatter<<<(E3c + 255) / 256, 256, 0, stream>>>(cube3, E3c, binStart3, cursor3, order3);
    {
        int maxBlk = (E3c + 255) / 256 + 64;
        spline_gemm<128><<<dim3(maxBlk, 2, 2), 256, 0, stream>>>(
            edge3, E3c, pseudo3, W3, xm3, order3, binStart3, binCnt3, blkPrefix3,
            chunkBin3, chunkOff3, agg3);
    }
    node_mm<128><<<(N3c * 128) / 256, 256, 0, stream>>>(agg3, deg3, xm3, root3, b3, x3, N3c);

    // pool 3: x3 -> xm4 (512 x 128) == (64 x 1024)
    segmax_scatter<<<(N3c * 128) / 256, 256, 0, stream>>>(x3, cluster3, (unsigned*)xm4, N3c * 128, 7);
    segmax_decode<<<(512 * 128) / 256, 256, 0, stream>>>((unsigned*)xm4, 512 * 128);

    // FC head
    fc1_k<<<64, 256, 0, stream>>>(xm4, fc1_w, fc1_b, h1);
    fc2_k<<<64, 64, 0, stream>>>(h1, fc2_w, fc2_b, out);
}